// Round 2
// baseline (126.052 us; speedup 1.0000x reference)
//
#include <hip/hip_runtime.h>

// ClusteringAffinity: out[n,c] = exp(-min_j (f[n]-W[c,j])^2 / 10) for c<100,
// out[n,100] = rw (pairwise-variance regularizer over the 500 centers).
//
// R1: scalar dword stores (COLS=101 odd -> no aligned float4 per row) ran the
// write stream at ~1-2 TB/s vs the 6.4 TB/s the harness fill achieves.
// R2 structure: compute a 64-row x 101-col tile into LDS, then stream the tile
// to global as contiguous 16B-aligned float4s (tile byte base = blk*25856 % 16 == 0).
// R3: the separate 1-block rw_kernel serialized the whole grid behind a
// 0.4%-occupancy dispatch. Fuse it: every block redundantly computes rw from
// closed-form power sums (500 values, fp64 wave butterfly, ~600 cyc, hidden
// under other blocks' store streams). Blocks widened to 512 threads
// (404 compute threads x 16 rows) for shorter per-block critical path.
// R4: R3 bench was an infra failure (container acquire), not a kernel fault —
// resubmitting unchanged for a real measurement.

static constexpr int N_    = 262144;
static constexpr int C_    = 100;
static constexpr int M_    = 5;
static constexpr int COLS  = C_ + 1;       // 101
static constexpr int MC_   = C_ * M_;      // 500
static constexpr int ROWS  = 64;           // rows per tile/block
static constexpr int TILE  = ROWS * COLS;  // 6464 floats = 25856 B (16B-aligned tiles)
static constexpr float SIGMA_INV = 0.1f;

__global__ __launch_bounds__(512)
void fused_affinity_kernel(const float* __restrict__ f,
                           const float* __restrict__ W,
                           float* __restrict__ out) {
    __shared__ __align__(16) float tile[TILE];
    __shared__ float rw_s;
    const int t  = threadIdx.x;
    const int n0 = blockIdx.x * ROWS;

    // ---- phase 0: rw regularizer, computed redundantly per block ----
    // sum_{i<j}(wi-wj)^2 and ^4 from power sums p1..p4 (fp64 for the
    // cancellation in S1 = mc*p2 - p1^2). Wave butterfly + tiny LDS stage.
    {
        double w = (t < MC_) ? (double)W[t] : 0.0;
        double p1 = w;
        double p2 = w * w;
        double p3 = p2 * w;
        double p4 = p2 * p2;
#pragma unroll
        for (int m = 32; m >= 1; m >>= 1) {
            p1 += __shfl_xor(p1, m, 64);
            p2 += __shfl_xor(p2, m, 64);
            p3 += __shfl_xor(p3, m, 64);
            p4 += __shfl_xor(p4, m, 64);
        }
        double* sc = (double*)tile;  // reuse tile as scratch (256 B), dead after
        if ((t & 63) == 0) {
            const int wv = t >> 6;
            sc[wv * 4 + 0] = p1;
            sc[wv * 4 + 1] = p2;
            sc[wv * 4 + 2] = p3;
            sc[wv * 4 + 3] = p4;
        }
        __syncthreads();
        if (t == 0) {
            double q1 = 0.0, q2 = 0.0, q3 = 0.0, q4 = 0.0;
            for (int i = 0; i < 8; ++i) {
                q1 += sc[i * 4 + 0];
                q2 += sc[i * 4 + 1];
                q3 += sc[i * 4 + 2];
                q4 += sc[i * 4 + 3];
            }
            const double mc = (double)MC_;
            const double P  = 0.5 * (mc * mc - mc);
            const double S1 = mc * q2 - q1 * q1;                       // sum_{i<j}(wi-wj)^2
            const double Sq = mc * q4 - 4.0 * q3 * q1 + 3.0 * q2 * q2; // sum_{i<j}(wi-wj)^4
            const double mu = S1 / P;
            rw_s = (float)(Sq / P - mu * mu);
        }
        __syncthreads();  // rw_s visible; tile scratch dead; compute may begin
    }

    // ---- phase 1: threads 0..403 each own one column for 16 rows ----
    if (t < 4 * COLS) {
        const int rq = t / COLS;                  // row quarter: rows rq*16..rq*16+15
        const int c  = t - rq * COLS;             // 0..100
        const int r0 = rq * 16;

        // 16 consecutive f values: 4 aligned float4 loads (L1-broadcast across threads)
        float fv[16];
        const float4* f4 = (const float4*)(f + n0 + r0);
#pragma unroll
        for (int q = 0; q < 4; ++q) {
            const float4 v = f4[q];
            fv[q * 4 + 0] = v.x; fv[q * 4 + 1] = v.y;
            fv[q * 4 + 2] = v.z; fv[q * 4 + 3] = v.w;
        }

        const int wc = (c < C_) ? c : 0;          // branch-free rw-column handling
        const float w0 = W[wc * M_ + 0];
        const float w1 = W[wc * M_ + 1];
        const float w2 = W[wc * M_ + 2];
        const float w3 = W[wc * M_ + 3];
        const float w4 = W[wc * M_ + 4];
        const float rw = rw_s;
        const bool is_dist = (c < C_);

        float* trow = tile + r0 * COLS + c;
#pragma unroll
        for (int i = 0; i < 16; ++i) {
            const float fk = fv[i];
            const float d0 = fk - w0, d1 = fk - w1, d2 = fk - w2,
                        d3 = fk - w3, d4 = fk - w4;
            const float m01 = fminf(d0 * d0, d1 * d1);
            const float m23 = fminf(d2 * d2, d3 * d3);
            const float mv  = fminf(fminf(m01, m23), d4 * d4);
            const float v   = __expf(-mv * SIGMA_INV);
            trow[i * COLS] = is_dist ? v : rw;    // consecutive-c lanes -> no bank conflict
        }
    }
    __syncthreads();

    // ---- phase 2: stream tile to global as aligned contiguous float4 ----
    const float4* lsrc = (const float4*)tile;
    float4* gdst = (float4*)(out + (size_t)n0 * COLS);  // blk*25856 B, 16B-aligned
    constexpr int NV = TILE / 4;  // 1616 float4s
#pragma unroll
    for (int q = 0; q < 3; ++q) {
        const int j = q * 512 + t;
        gdst[j] = lsrc[j];
    }
    {
        const int j = 3 * 512 + t;
        if (j < NV) gdst[j] = lsrc[j];
    }
}

extern "C" void kernel_launch(void* const* d_in, const int* in_sizes, int n_in,
                              void* d_out, int out_size, void* d_ws, size_t ws_size,
                              hipStream_t stream) {
    const float* f   = (const float*)d_in[0];   // (262144, 1) fp32
    const float* W   = (const float*)d_in[1];   // (100, 5, 1) fp32
    float*       out = (float*)d_out;           // (262144, 101) fp32
    (void)d_ws; (void)ws_size;

    fused_affinity_kernel<<<N_ / ROWS, 512, 0, stream>>>(f, W, out);
}

// Round 3
// 117.924 us; speedup vs baseline: 1.0689x; 1.0689x over previous
//
#include <hip/hip_runtime.h>

// ClusteringAffinity: out[n,c] = exp(-min_j (f[n]-W[c,j])^2 / 10) for c<100,
// out[n,100] = rw (pairwise-variance regularizer over the 500 centers).
//
// R1: scalar dword stores (COLS=101 odd -> no aligned float4 per row) ran the
// write stream at ~1-2 TB/s vs the 6.4 TB/s the harness fill achieves.
// R2 structure: compute a 64-row x 101-col tile into LDS, then stream the tile
// to global as contiguous 16B-aligned float4s (tile byte base = blk*25856 % 16 == 0).
// R3 (regressed, 126 vs 120): fused rw as a BLOCKING prologue (butterfly +
// thread-0 fp64 serial section between two barriers) — all 8 waves of every
// block idled behind it.
// R4 (this round): rw fused at ZERO cost. Compute threads = 0..399 (4 row-
// quarters x 100 distance columns); wave 7 (t 448..511, fully idle in the old
// mapping) computes rw concurrently: per-lane fp64 power sums over ~8 W values,
// one 6-step butterfly (all lanes get totals), no divides (multiply by
// precomputed 1/P), lane r writes tile[r*101+100] (stride 101 -> conflict-free).
// No extra barriers vs the R0 affinity kernel; one dispatch total.

static constexpr int N_    = 262144;
static constexpr int C_    = 100;
static constexpr int M_    = 5;
static constexpr int COLS  = C_ + 1;       // 101
static constexpr int MC_   = C_ * M_;      // 500
static constexpr int ROWS  = 64;           // rows per tile/block
static constexpr int TILE  = ROWS * COLS;  // 6464 floats = 25856 B (16B-aligned tiles)
static constexpr float SIGMA_INV = 0.1f;

__global__ __launch_bounds__(512)
void fused_affinity_kernel(const float* __restrict__ f,
                           const float* __restrict__ W,
                           float* __restrict__ out) {
    __shared__ __align__(16) float tile[TILE];
    const int t  = threadIdx.x;
    const int n0 = blockIdx.x * ROWS;

    if (t < 400) {
        // ---- distance columns: thread owns column c for 16 rows ----
        const int rq = t / 100;                   // row quarter: rows rq*16..rq*16+15
        const int c  = t - rq * 100;              // 0..99
        const int r0 = rq * 16;

        // 16 consecutive f values: 4 aligned float4 loads (L1-broadcast across threads)
        float fv[16];
        const float4* f4 = (const float4*)(f + n0 + r0);
#pragma unroll
        for (int q = 0; q < 4; ++q) {
            const float4 v = f4[q];
            fv[q * 4 + 0] = v.x; fv[q * 4 + 1] = v.y;
            fv[q * 4 + 2] = v.z; fv[q * 4 + 3] = v.w;
        }

        const float w0 = W[c * M_ + 0];
        const float w1 = W[c * M_ + 1];
        const float w2 = W[c * M_ + 2];
        const float w3 = W[c * M_ + 3];
        const float w4 = W[c * M_ + 4];

        float* trow = tile + r0 * COLS + c;
#pragma unroll
        for (int i = 0; i < 16; ++i) {
            const float fk = fv[i];
            const float d0 = fk - w0, d1 = fk - w1, d2 = fk - w2,
                        d3 = fk - w3, d4 = fk - w4;
            const float m01 = fminf(d0 * d0, d1 * d1);
            const float m23 = fminf(d2 * d2, d3 * d3);
            const float mv  = fminf(fminf(m01, m23), d4 * d4);
            trow[i * COLS] = __expf(-mv * SIGMA_INV);  // consecutive-c lanes -> no conflict
        }
    } else if (t >= 448) {
        // ---- rw column: wave 7 (otherwise idle) computes the regularizer ----
        // Closed form from power sums p1..p4 (fp64 for the S1 = mc*p2 - p1^2
        // cancellation): sum_{i<j}(wi-wj)^2 = mc*p2 - p1^2,
        //               sum_{i<j}(wi-wj)^4 = mc*p4 - 4*p3*p1 + 3*p2^2.
        const int l = t - 448;                    // lane 0..63 of wave 7
        double p1 = 0.0, p2 = 0.0, p3 = 0.0, p4 = 0.0;
#pragma unroll
        for (int k = 0; k < 8; ++k) {
            const int idx = l + 64 * k;
            const double w = (idx < MC_) ? (double)W[idx] : 0.0;
            const double w2 = w * w;
            p1 += w; p2 += w2; p3 += w2 * w; p4 += w2 * w2;
        }
#pragma unroll
        for (int m = 32; m >= 1; m >>= 1) {       // butterfly: all lanes get totals
            p1 += __shfl_xor(p1, m, 64);
            p2 += __shfl_xor(p2, m, 64);
            p3 += __shfl_xor(p3, m, 64);
            p4 += __shfl_xor(p4, m, 64);
        }
        const double mc   = (double)MC_;
        const double PINV = 1.0 / 124750.0;       // 1 / (0.5*(mc^2-mc)), no fp64 div
        const double S1 = mc * p2 - p1 * p1;
        const double Sq = mc * p4 - 4.0 * p3 * p1 + 3.0 * p2 * p2;
        const double mu = S1 * PINV;
        const float  rw = (float)(Sq * PINV - mu * mu);
        // lane r -> row r, col 100; addr stride 101 across lanes (101%32=5,
        // coprime with 32) -> 2 lanes/bank, conflict-free.
        tile[l * COLS + C_] = rw;
    }
    __syncthreads();

    // ---- store phase: stream tile to global as aligned contiguous float4 ----
    const float4* lsrc = (const float4*)tile;
    float4* gdst = (float4*)(out + (size_t)n0 * COLS);  // blk*25856 B, 16B-aligned
    constexpr int NV = TILE / 4;  // 1616 float4s
#pragma unroll
    for (int q = 0; q < 3; ++q) {
        const int j = q * 512 + t;
        gdst[j] = lsrc[j];
    }
    {
        const int j = 3 * 512 + t;
        if (j < NV) gdst[j] = lsrc[j];
    }
}

extern "C" void kernel_launch(void* const* d_in, const int* in_sizes, int n_in,
                              void* d_out, int out_size, void* d_ws, size_t ws_size,
                              hipStream_t stream) {
    const float* f   = (const float*)d_in[0];   // (262144, 1) fp32
    const float* W   = (const float*)d_in[1];   // (100, 5, 1) fp32
    float*       out = (float*)d_out;           // (262144, 101) fp32
    (void)d_ws; (void)ws_size;

    fused_affinity_kernel<<<N_ / ROWS, 512, 0, stream>>>(f, W, out);
}